// Round 4
// baseline (641.721 us; speedup 1.0000x reference)
//
#include <hip/hip_runtime.h>
#include <hip/hip_bf16.h>

// Transposed conv (full conv): out[b,p,q,co] = sum_{kh,kw,ci} in[b,p-kh,q-kw,ci]*K[ci,co,kh,kw]
// B=8 H=W=256 C=64, out 8x258x258x64 fp32. bf16 MFMA path.
//
// R3: persistent blocks + LDS double buffer. 512-thr block, 32x16 tile,
// grid-stride over 1224 tiles. Per iter: issue next tile's global loads (regs),
// compute current tile (full tap unroll, B-frags from L2-hot wsW), store C,
// convert+ds_write next tile, one barrier. Loads in flight during all compute.

#define OH 258
#define OW 258
#define NT_Q 17
#define NT_P 9
#define NTILES (NT_Q * NT_P * 8)   // 1224
#define GRID 256
#define PATCH_PIX 612              // 34 rows x 18 cols
#define GRAN (PATCH_PIX * 8)       // 4896 16B-bf16 granules per tile
#define BUFE (PATCH_PIX * 64)      // elems per LDS buffer

typedef __bf16 bf16x8 __attribute__((ext_vector_type(8)));
typedef float  f32x4  __attribute__((ext_vector_type(4)));

// ws layout: wsW[((tap*2+s)*64+co)*32 + c] = K[ci=32s+c][co][kh][kw], tap=kh*3+kw
__global__ void prep_w_kernel(const float* __restrict__ k, __bf16* __restrict__ wsW) {
    int i = blockIdx.x * 256 + threadIdx.x;            // [0, 36864)
    int c  = i & 31;
    int co = (i >> 5) & 63;
    int st = i >> 11;
    int s   = st & 1;
    int tap = st >> 1;
    int kh = tap / 3, kw = tap % 3;
    float v = k[(s * 32 + c) * 576 + co * 9 + kh * 3 + kw];
    wsW[i] = (__bf16)v;
}

__device__ __forceinline__ void tile_coords(int t, int& p0, int& q0, int& bb) {
    int tq = t % NT_Q;
    int r  = t / NT_Q;
    p0 = (r % NT_P) * 32;
    q0 = tq * 16;
    bb = r / NT_P;
}

__global__ __launch_bounds__(512, 2)
void tconv_kernel(const float* __restrict__ in, const __bf16* __restrict__ wsW,
                  float* __restrict__ out) {
    __shared__ __bf16 lds[2 * BUFE];   // 156672 B -> 1 block/CU

    const int tid  = threadIdx.x;
    const int wv   = tid >> 6, lane = tid & 63;
    const int ml   = lane & 15, h = lane >> 4;
    const int woff = ml * 32 + h * 8;

    // ---- issue: clamped-address unconditional loads for tile t into regs
    auto issue = [&](int t, f32x4* va, f32x4* vb) {
        int p0, q0, bb; tile_coords(t, p0, q0, bb);
        #pragma unroll
        for (int k = 0; k < 10; ++k) {
            int it = tid + k * 512;
            if (it < GRAN) {
                int pix = it >> 3, c8 = it & 7;
                int r = pix / 18, c = pix - r * 18;
                int ip = p0 - 2 + r, iq = q0 - 2 + c;
                bool inb = ((unsigned)ip < 256u) & ((unsigned)iq < 256u);
                const float* g = in + (((size_t)bb * 256 + (inb ? ip : 0)) * 256
                                       + (inb ? iq : 0)) * 64 + c8 * 8;
                va[k] = *(const f32x4*)g;
                vb[k] = *(const f32x4*)(g + 4);
            }
        }
    };

    // ---- commit: convert (zero OOB) + swizzled ds_write into dst buffer
    auto commit = [&](int t, __bf16* dst, const f32x4* va, const f32x4* vb) {
        int p0, q0, bb; tile_coords(t, p0, q0, bb);
        #pragma unroll
        for (int k = 0; k < 10; ++k) {
            int it = tid + k * 512;
            if (it < GRAN) {
                int pix = it >> 3, c8 = it & 7;
                int r = pix / 18, c = pix - r * 18;
                int ip = p0 - 2 + r, iq = q0 - 2 + c;
                bool inb = ((unsigned)ip < 256u) & ((unsigned)iq < 256u);
                bf16x8 w;
                #pragma unroll
                for (int e = 0; e < 4; ++e) {
                    w[e]     = (__bf16)(inb ? va[k][e] : 0.f);
                    w[e + 4] = (__bf16)(inb ? vb[k][e] : 0.f);
                }
                *(bf16x8*)&dst[pix * 64 + ((c8 ^ (pix & 7)) * 8)] = w;
            }
        }
    };

    // ---- prologue: stage first tile synchronously into buf 0
    int t0 = blockIdx.x;
    {
        f32x4 va[10], vb[10];
        issue(t0, va, vb);
        commit(t0, lds, va, vb);
    }
    __syncthreads();

    int cur = 0;
    #pragma unroll 1
    for (int t = t0; t < NTILES; t += GRID, cur ^= 1) {
        f32x4 va[10], vb[10];
        const int tn = t + GRID;
        if (tn < NTILES) issue(tn, va, vb);

        int p0, q0, bb; tile_coords(t, p0, q0, bb);
        const __bf16* src = lds + cur * BUFE;

        f32x4 acc[4][4] = {};
        #pragma unroll
        for (int tap = 0; tap < 9; ++tap) {
            const int kh = tap / 3, kw = tap - kh * 3;
            const __bf16* wt = wsW + tap * 4096;
            #pragma unroll
            for (int s = 0; s < 2; ++s) {
                bf16x8 bfr[4];
                #pragma unroll
                for (int nt = 0; nt < 4; ++nt)
                    bfr[nt] = *(const bf16x8*)(wt + s * 2048 + nt * 512 + woff);
                const int j = s * 4 + h;
                #pragma unroll
                for (int mt = 0; mt < 4; ++mt) {
                    int row = wv * 4 + mt + 2 - kh;
                    int pix = row * 18 + (2 - kw) + ml;
                    bf16x8 afr = *(const bf16x8*)&src[pix * 64 + ((j ^ (pix & 7)) * 8)];
                    #pragma unroll
                    for (int nt = 0; nt < 4; ++nt)
                        acc[mt][nt] = __builtin_amdgcn_mfma_f32_16x16x32_bf16(
                            afr, bfr[nt], acc[mt][nt], 0, 0, 0);
                }
            }
        }

        // ---- C stores (D layout: col(co)=ml, row(q)=h*4+reg)
        #pragma unroll
        for (int mt = 0; mt < 4; ++mt) {
            int p = p0 + wv * 4 + mt;
            if (p < OH) {
                int qb = q0 + h * 4;
                #pragma unroll
                for (int nt = 0; nt < 4; ++nt) {
                    float* op = out + (((size_t)bb * OH + p) * OW + qb) * 64 + nt * 16 + ml;
                    #pragma unroll
                    for (int r = 0; r < 4; ++r)
                        if (qb + r < OW) op[(size_t)r * 64] = acc[mt][nt][r];
                }
            }
        }

        if (tn < NTILES) commit(tn, lds + (cur ^ 1) * BUFE, va, vb);
        __syncthreads();
    }
}

extern "C" void kernel_launch(void* const* d_in, const int* in_sizes, int n_in,
                              void* d_out, int out_size, void* d_ws, size_t ws_size,
                              hipStream_t stream) {
    (void)in_sizes; (void)n_in; (void)out_size; (void)ws_size;
    const float* in   = (const float*)d_in[0];
    const float* kern = (const float*)d_in[1];
    float* out = (float*)d_out;
    __bf16* wsW = (__bf16*)d_ws;   // 36864 bf16 = 73728 B

    prep_w_kernel<<<144, 256, 0, stream>>>(kern, wsW);
    tconv_kernel<<<GRID, 512, 0, stream>>>(in, wsW, out);
}